// Round 2
// baseline (319.067 us; speedup 1.0000x reference)
//
#include <hip/hip_runtime.h>

// Problem constants
#define QN    2048          // queries
#define SS    8             // frames per video
#define DD    2048          // feature dim
#define SP    100           // support videos
#define NCLS  20
#define MROWS (QN*SS)       // 16384 GEMM M
#define NROWS (SP*SS)       // 800   GEMM N (logical)
#define NPAD  896           // N padded to 7*128
#define KK    DD            // 2048  GEMM K

typedef __bf16 bf16x8 __attribute__((ext_vector_type(8)));
typedef float  f32x4  __attribute__((ext_vector_type(4)));

__device__ __forceinline__ unsigned short f2bf(float f) {
    unsigned int u = __float_as_uint(f);
    u += 0x7fffu + ((u >> 16) & 1u);   // round-to-nearest-even
    return (unsigned short)(u >> 16);
}

// ---------------- Kernel 1: fp32 -> bf16 conversion + row L2 norms ----------------
__global__ void cvt_kernel(const float* __restrict__ tf, const float* __restrict__ sf,
                           unsigned short* __restrict__ Abf, unsigned short* __restrict__ Bbf,
                           float* __restrict__ nA, float* __restrict__ nB)
{
    int row = blockIdx.x;
    int tid = threadIdx.x;
    const float* src = nullptr;
    unsigned short* dst;
    float* nrm; int r;
    if (row < MROWS) { src = tf + (size_t)row * DD; dst = Abf + (size_t)row * DD; nrm = nA; r = row; }
    else {
        r = row - MROWS;
        dst = Bbf + (size_t)r * DD; nrm = nB;
        if (r < NROWS) src = sf + (size_t)r * DD;   // rows [800,896) stay zero
    }
    float s = 0.f;
    union { uint4 u; unsigned short h[8]; } pk;
    if (src) {
        float4 v0 = *(const float4*)(src + tid * 8);
        float4 v1 = *(const float4*)(src + tid * 8 + 4);
        s = v0.x*v0.x + v0.y*v0.y + v0.z*v0.z + v0.w*v0.w
          + v1.x*v1.x + v1.y*v1.y + v1.z*v1.z + v1.w*v1.w;
        pk.h[0]=f2bf(v0.x); pk.h[1]=f2bf(v0.y); pk.h[2]=f2bf(v0.z); pk.h[3]=f2bf(v0.w);
        pk.h[4]=f2bf(v1.x); pk.h[5]=f2bf(v1.y); pk.h[6]=f2bf(v1.z); pk.h[7]=f2bf(v1.w);
    } else {
        pk.u = make_uint4(0, 0, 0, 0);
    }
    *(uint4*)(dst + (size_t)tid * 8) = pk.u;

    for (int o = 32; o; o >>= 1) s += __shfl_down(s, o);
    __shared__ float red[4];
    if ((tid & 63) == 0) red[tid >> 6] = s;
    __syncthreads();
    if (tid == 0) nrm[r] = sqrtf(red[0] + red[1] + red[2] + red[3]);
}

// ---------------- softmin helpers ----------------
__device__ __forceinline__ float softmin2(float a, float b) {
    float mn = fminf(a, b), mx = fmaxf(a, b);
    return mn - 0.1f * __logf(1.0f + __expf((mn - mx) * 10.0f));
}
__device__ __forceinline__ float softmin3(float a, float b, float c) {
    float mn = fminf(fminf(a, b), c);
    float sum = __expf((mn - a) * 10.0f) + __expf((mn - b) * 10.0f) + __expf((mn - c) * 10.0f);
    return mn - 0.1f * __logf(sum);
}

// ---------------- Kernel 2: bf16 MFMA GEMM + fused epilogue:
//   dist = 1 - dot/(nx*ny+eps), then OTAM DP (both dirs) per (q,sp) pair -> cum ----
__device__ __forceinline__ void gld16(const void* g, void* l) {
    __builtin_amdgcn_global_load_lds(
        (const __attribute__((address_space(1))) unsigned int*)g,
        (__attribute__((address_space(3))) unsigned int*)l, 16, 0, 0);
}

#define EPB (32 * 65)   // per-wave epilogue buffer: 32 rows x 64 cols, stride 65 (pad)

__global__ __launch_bounds__(256, 2) void gemm_kernel(
    const unsigned short* __restrict__ A,   // [MROWS][K] bf16 bits
    const unsigned short* __restrict__ B,   // [NPAD][K]  bf16 bits
    const float* __restrict__ nA, const float* __restrict__ nB,
    float* __restrict__ cum)                // [QN][SP]
{
    // LDS: staging (16 KB) aliased with epilogue buffers (4 waves x 8320 B = 33280 B)
    __shared__ __align__(16) char smem[4 * EPB * 4];
    unsigned short* Als = (unsigned short*)smem;            // 128*32 shorts
    unsigned short* Bls = Als + 128 * 32;

    const int mt  = blockIdx.x;      // 0..127
    const int nt  = blockIdx.y;      // 0..6
    const int tid = threadIdx.x;
    const int lane = tid & 63;
    const int w    = tid >> 6;
    const int wm   = (w & 1) * 64, wn = (w >> 1) * 64;
    const int col  = lane & 15, kg = lane >> 4;

    f32x4 acc[4][4] = {};

    // staging: 512 16B-chunks per tile, 2 per thread.
    // LDS slot c is hardware-fixed (wave base + lane*16); we choose which global
    // chunk lands there: slot c <- global (row = c>>2, ksub = (c&3) ^ ((c>>3)&3)).
    // XOR swizzle makes the fragment ds_read_b128 bank-conflict-free.
    const int c0 = tid, c1 = tid + 256;
    const int r0 = c0 >> 2, k0 = ((c0 & 3) ^ ((c0 >> 3) & 3)) * 8;
    const int r1 = c1 >> 2, k1 = ((c1 & 3) ^ ((c1 >> 3) & 3)) * 8;
    const unsigned short* Ab0 = A + (size_t)mt * 128 * KK + (size_t)r0 * KK + k0;
    const unsigned short* Ab1 = A + (size_t)mt * 128 * KK + (size_t)r1 * KK + k1;
    const unsigned short* Bb0 = B + (size_t)nt * 128 * KK + (size_t)r0 * KK + k0;
    const unsigned short* Bb1 = B + (size_t)nt * 128 * KK + (size_t)r1 * KK + k1;

    const int ksw = (kg ^ ((col >> 1) & 3)) * 8;   // swizzled k-sub offset for reads

    for (int kk = 0; kk < KK; kk += 32) {
        __syncthreads();
        gld16(Ab0 + kk, (char*)Als + c0 * 16);
        gld16(Ab1 + kk, (char*)Als + c1 * 16);
        gld16(Bb0 + kk, (char*)Bls + c0 * 16);
        gld16(Bb1 + kk, (char*)Bls + c1 * 16);
        __syncthreads();
        bf16x8 af[4], bfr[4];
#pragma unroll
        for (int i = 0; i < 4; i++) af[i]  = *(const bf16x8*)(Als + (wm + i * 16 + col) * 32 + ksw);
#pragma unroll
        for (int i = 0; i < 4; i++) bfr[i] = *(const bf16x8*)(Bls + (wn + i * 16 + col) * 32 + ksw);
#pragma unroll
        for (int mi = 0; mi < 4; mi++)
#pragma unroll
            for (int ni = 0; ni < 4; ni++)
                acc[mi][ni] = __builtin_amdgcn_mfma_f32_16x16x32_bf16(af[mi], bfr[ni], acc[mi][ni], 0, 0, 0);
    }

    // ---------------- fused epilogue: dist -> LDS -> OTAM DP -> cum ----------------
    const int mbase = mt * 128 + wm;
    const int nbase = nt * 128 + wn;
    const int qv0 = mt * 16 + (wm >> 3);   // first q-video of this wave's 64 rows
    const int sv0 = nt * 16 + (wn >> 3);   // first s-video of this wave's 64 cols
    float* eb = (float*)smem + w * EPB;

    const int qv2 = (lane >> 3) & 3;       // pair row-video within phase (0..3)
    const int sv  = lane & 7;              // pair col-video within wave (0..7)
    const int dir = lane >> 5;             // 0: rows=L, 1: transposed

#pragma unroll
    for (int p = 0; p < 2; p++) {
        __syncthreads();   // staging LDS dead / previous phase reads done
        // write rows [p*32, p*32+32) of this wave's 64x64 dist sub-tile
#pragma unroll
        for (int mi2 = 0; mi2 < 2; mi2++) {
            const int mi = p * 2 + mi2;
            const float nx0 = nA[mbase + mi * 16 + kg * 4 + 0];
            const float nx1 = nA[mbase + mi * 16 + kg * 4 + 1];
            const float nx2 = nA[mbase + mi * 16 + kg * 4 + 2];
            const float nx3 = nA[mbase + mi * 16 + kg * 4 + 3];
#pragma unroll
            for (int ni = 0; ni < 4; ni++) {
                const float ny = nB[nbase + ni * 16 + col];
                float* dstp = eb + (mi2 * 16 + kg * 4) * 65 + ni * 16 + col;
                dstp[0]      = 1.0f - acc[mi][ni][0] / (nx0 * ny + 0.01f);
                dstp[65]     = 1.0f - acc[mi][ni][1] / (nx1 * ny + 0.01f);
                dstp[130]    = 1.0f - acc[mi][ni][2] / (nx2 * ny + 0.01f);
                dstp[195]    = 1.0f - acc[mi][ni][3] / (nx3 * ny + 0.01f);
            }
        }
        __syncthreads();   // make this wave's LDS writes visible to its own lanes

        // DP: 32 pairs x 2 directions = 64 lanes
        const float* tb = eb + (qv2 * 8) * 65 + sv * 8;
        // row 0 cumsum
        float prev[10], cur[10];
        prev[0] = 0.f;
#pragma unroll
        for (int m = 1; m <= 8; m++)
            prev[m] = prev[m - 1] + (dir ? tb[(m - 1) * 65] : tb[m - 1]);
        prev[9] = prev[8];
#pragma unroll
        for (int l = 1; l < 8; l++) {
            float d[8];
#pragma unroll
            for (int j = 0; j < 8; j++) d[j] = dir ? tb[j * 65 + l] : tb[l * 65 + j];
            cur[0] = 0.f;
            cur[1] = d[0] + softmin3(prev[0], prev[1], 0.0f);
#pragma unroll
            for (int m = 2; m <= 8; m++)
                cur[m] = d[m - 1] + softmin2(prev[m - 1], cur[m - 1]);
            cur[9] = softmin3(prev[8], prev[9], cur[8]);   // pad column: d=0
#pragma unroll
            for (int m = 0; m < 10; m++) prev[m] = cur[m];
        }
        float res = prev[9];
        res += __shfl_down(res, 32);    // combine the two directions
        if (dir == 0) {
            const int qg = qv0 + p * 4 + qv2;
            const int sg = sv0 + sv;
            if (sg < SP) cum[(size_t)qg * SP + sg] = res;
        }
    }
}

// ---------------- Kernel 3: per-class mean -> logits ----------------
__global__ void cls_kernel(const float* __restrict__ cum, const int* __restrict__ labels,
                           float* __restrict__ out)
{
    int idx = blockIdx.x * 256 + threadIdx.x;   // 40960 exactly
    int q = idx / NCLS, c = idx % NCLS;
    float s = 0.f; int n = 0;
    const float* row = cum + (size_t)q * SP;
    for (int sp = 0; sp < SP; sp++) {
        if (labels[sp] == c) { s += row[sp]; n++; }
    }
    out[idx] = -s / (float)n;
}

// ---------------- launch ----------------
extern "C" void kernel_launch(void* const* d_in, const int* in_sizes, int n_in,
                              void* d_out, int out_size, void* d_ws, size_t ws_size,
                              hipStream_t stream)
{
    const float* tf     = (const float*)d_in[0];   // [2048,8,2048] f32
    const float* sf     = (const float*)d_in[1];   // [100,8,2048]  f32
    const int*   labels = (const int*)d_in[2];     // [100] i32
    float* out = (float*)d_out;                    // [1,2048,20] f32

    char* ws = (char*)d_ws;
    const size_t szA    = (size_t)MROWS * KK * 2;      // 67108864
    const size_t szB    = (size_t)NPAD  * KK * 2;      // 3670016
    const size_t szNA   = (size_t)MROWS * 4;           // 65536
    const size_t szNB   = (size_t)NPAD  * 4;           // 3584
    unsigned short* Abf = (unsigned short*)ws;
    unsigned short* Bbf = (unsigned short*)(ws + szA);
    float* nA   = (float*)(ws + szA + szB);
    float* nB   = (float*)(ws + szA + szB + szNA);
    float* cum  = (float*)(ws + szA + szB + szNA + szNB);   // [2048][100]

    cvt_kernel<<<MROWS + NPAD, 256, 0, stream>>>(tf, sf, Abf, Bbf, nA, nB);
    gemm_kernel<<<dim3(128, 7), 256, 0, stream>>>(Abf, Bbf, nA, nB, cum);
    cls_kernel<<<160, 256, 0, stream>>>(cum, labels, out);
}